// Round 2
// baseline (927.358 us; speedup 1.0000x reference)
//
#include <hip/hip_runtime.h>

#define NROWS 16384
#define NCODES 8192
#define DIM 256
#define BM 64
#define BN 512
#define BKC 32
#define WPAD 4
#define NTHREADS 512
#define NTILES (NCODES / BN)    // 16
#define NCHUNKS (DIM / BKC)     // 8

// Replicate np.sum(x*x, axis=1) in fp32 EXACTLY (numpy pairwise summation).
// n=256 -> pairwise(0..127) + pairwise(128..255); each 128-block uses 8
// accumulators stride 8, combined ((r0+r1)+(r2+r3))+((r4+r5)+(r6+r7)).
__global__ __launch_bounds__(256) void xsq_kernel(const float* __restrict__ x,
                                                  float* __restrict__ xsq) {
    int row = blockIdx.x * 256 + threadIdx.x;
    const float4* p = reinterpret_cast<const float4*>(x + (size_t)row * DIM);
    float res[2];
    #pragma unroll
    for (int h = 0; h < 2; ++h) {
        float r[8];
        #pragma unroll
        for (int j = 0; j < 8; ++j) r[j] = 0.0f;
        #pragma unroll
        for (int g = 0; g < 16; ++g) {
            float4 v0 = p[h * 32 + g * 2];
            float4 v1 = p[h * 32 + g * 2 + 1];
            r[0] = __fadd_rn(r[0], __fmul_rn(v0.x, v0.x));
            r[1] = __fadd_rn(r[1], __fmul_rn(v0.y, v0.y));
            r[2] = __fadd_rn(r[2], __fmul_rn(v0.z, v0.z));
            r[3] = __fadd_rn(r[3], __fmul_rn(v0.w, v0.w));
            r[4] = __fadd_rn(r[4], __fmul_rn(v1.x, v1.x));
            r[5] = __fadd_rn(r[5], __fmul_rn(v1.y, v1.y));
            r[6] = __fadd_rn(r[6], __fmul_rn(v1.z, v1.z));
            r[7] = __fadd_rn(r[7], __fmul_rn(v1.w, v1.w));
        }
        res[h] = __fadd_rn(__fadd_rn(__fadd_rn(r[0], r[1]), __fadd_rn(r[2], r[3])),
                           __fadd_rn(__fadd_rn(r[4], r[5]), __fadd_rn(r[6], r[7])));
    }
    xsq[row] = __fadd_rn(res[0], res[1]);
}

// wsq: fp32, any order (tolerance analysis: ~1e-13 perturbation is harmless).
__global__ __launch_bounds__(256) void wsq_kernel(const float* __restrict__ w,
                                                  float* __restrict__ wsq) {
    int wave = threadIdx.x >> 6;
    int lane = threadIdx.x & 63;
    int code = blockIdx.x * 4 + wave;
    float4 v = reinterpret_cast<const float4*>(w + (size_t)code * DIM)[lane];
    float s = __fadd_rn(__fadd_rn(__fmul_rn(v.x, v.x), __fmul_rn(v.y, v.y)),
                        __fadd_rn(__fmul_rn(v.z, v.z), __fmul_rn(v.w, v.w)));
    #pragma unroll
    for (int off = 32; off > 0; off >>= 1)
        s += __shfl_xor(s, off, 64);
    if (lane == 0) wsq[code] = s;
}

__global__ __launch_bounds__(NTHREADS, 2)
void vq_argmin_kernel(const float* __restrict__ x, const float* __restrict__ w,
                      const float* __restrict__ wsq, const float* __restrict__ xsq,
                      float* __restrict__ out_q, float* __restrict__ out_idx) {
    __shared__ float xsT[DIM][BM];          // 64 KB, transposed x tile (resident)
    __shared__ float wsT[BKC][BN + WPAD];   // ~64.5 KB, transposed w chunk (pad: 4-way writes)
    __shared__ int rowBest[BM];

    const int tid = threadIdx.x;
    const int lane = tid & 63;
    const int wv = tid >> 6;                // 0..7
    const int rg = lane >> 3;               // 0..7  -> rows rg*8+i
    const int cg = wv * 8 + (lane & 7);     // 0..63 -> codes cg*8+j (within tile)
    const int rowBase = blockIdx.x * BM;

    // stage x tile transposed: xsT[k][r] = x[rowBase+r][k]
    #pragma unroll
    for (int it = 0; it < 8; ++it) {
        int flat = it * NTHREADS + tid;      // 0..4095
        int r = flat & 63;
        int kq = flat >> 6;                  // 0..63
        float4 v = reinterpret_cast<const float4*>(x + (size_t)(rowBase + r) * DIM)[kq];
        xsT[kq * 4 + 0][r] = v.x;
        xsT[kq * 4 + 1][r] = v.y;
        xsT[kq * 4 + 2][r] = v.z;
        xsT[kq * 4 + 3][r] = v.w;
    }

    float xsqr[8];
    {
        float4 a = reinterpret_cast<const float4*>(xsq + rowBase + rg * 8)[0];
        float4 b = reinterpret_cast<const float4*>(xsq + rowBase + rg * 8)[1];
        xsqr[0] = a.x; xsqr[1] = a.y; xsqr[2] = a.z; xsqr[3] = a.w;
        xsqr[4] = b.x; xsqr[5] = b.y; xsqr[6] = b.z; xsqr[7] = b.w;
    }

    float bestv[8];
    int   besti[8];
    #pragma unroll
    for (int i = 0; i < 8; ++i) { bestv[i] = __builtin_huge_valf(); besti[i] = 0; }

    for (int tile = 0; tile < NTILES; ++tile) {
        float acc[8][8];
        #pragma unroll
        for (int i = 0; i < 8; ++i)
            #pragma unroll
            for (int j = 0; j < 8; ++j) acc[i][j] = 0.0f;

        for (int chunk = 0; chunk < NCHUNKS; ++chunk) {
            __syncthreads();
            // stage w chunk transposed: wsT[kk][c] = w[tile*BN+c][chunk*BKC+kk]
            #pragma unroll
            for (int it = 0; it < 8; ++it) {
                int flat = it * NTHREADS + tid;  // 0..4095
                int c = flat >> 3;               // 0..511
                int kq = flat & 7;               // 0..7
                float4 v = reinterpret_cast<const float4*>(
                    w + (size_t)(tile * BN + c) * DIM + chunk * BKC)[kq];
                wsT[kq * 4 + 0][c] = v.x;
                wsT[kq * 4 + 1][c] = v.y;
                wsT[kq * 4 + 2][c] = v.z;
                wsT[kq * 4 + 3][c] = v.w;
            }
            __syncthreads();

            // k-ascending single-chain FMA accumulation (matches OpenBLAS sgemm)
            #pragma unroll 4
            for (int kk = 0; kk < BKC; ++kk) {
                const float* xrow = &xsT[chunk * BKC + kk][0];
                const float* wrow = &wsT[kk][0];
                float4 xa0 = *reinterpret_cast<const float4*>(xrow + rg * 8);
                float4 xa1 = *reinterpret_cast<const float4*>(xrow + rg * 8 + 4);
                float4 wb0 = *reinterpret_cast<const float4*>(wrow + cg * 8);
                float4 wb1 = *reinterpret_cast<const float4*>(wrow + cg * 8 + 4);
                float xa[8] = {xa0.x, xa0.y, xa0.z, xa0.w, xa1.x, xa1.y, xa1.z, xa1.w};
                float wb[8] = {wb0.x, wb0.y, wb0.z, wb0.w, wb1.x, wb1.y, wb1.z, wb1.w};
                #pragma unroll
                for (int i = 0; i < 8; ++i)
                    #pragma unroll
                    for (int j = 0; j < 8; ++j)
                        acc[i][j] = fmaf(xa[i], wb[j], acc[i][j]);
            }
        }

        // d = fl32( fl32(xsq + wsq) - 2*dot ), argmin first-index
        float wq[8];
        {
            float4 a = reinterpret_cast<const float4*>(wsq + tile * BN + cg * 8)[0];
            float4 b = reinterpret_cast<const float4*>(wsq + tile * BN + cg * 8)[1];
            wq[0] = a.x; wq[1] = a.y; wq[2] = a.z; wq[3] = a.w;
            wq[4] = b.x; wq[5] = b.y; wq[6] = b.z; wq[7] = b.w;
        }
        #pragma unroll
        for (int j = 0; j < 8; ++j) {
            int c = tile * BN + cg * 8 + j;
            #pragma unroll
            for (int i = 0; i < 8; ++i) {
                float t1 = __fadd_rn(xsqr[i], wq[j]);
                float s = __fsub_rn(t1, __fadd_rn(acc[i][j], acc[i][j]));  // 2*acc exact
                if (s < bestv[i]) { bestv[i] = s; besti[i] = c; }
            }
        }
    }

    // cross-thread argmin reduction (64 candidates per row), index tie-break
    __syncthreads();
    float* redv = &xsT[0][0];                       // 4096 floats
    int* redi = reinterpret_cast<int*>(&xsT[0][0]) + 4096;
    #pragma unroll
    for (int i = 0; i < 8; ++i) {
        int r = rg * 8 + i;
        redv[r * 64 + cg] = bestv[i];
        redi[r * 64 + cg] = besti[i];
    }
    __syncthreads();
    if (tid < BM) {
        float bv = redv[tid * 64];
        int bi = redi[tid * 64];
        for (int t = 1; t < 64; ++t) {
            float v = redv[tid * 64 + t];
            int ci = redi[tid * 64 + t];
            if (v < bv || (v == bv && ci < bi)) { bv = v; bi = ci; }
        }
        rowBest[tid] = bi;
        out_idx[rowBase + tid] = (float)bi;  // exact for idx < 2^24
    }
    __syncthreads();

    // gather winning codewords, coalesced float4
    int r8 = tid >> 6;
    #pragma unroll
    for (int it2 = 0; it2 < 8; ++it2) {
        int r = it2 * 8 + r8;
        int code = rowBest[r];
        float4 v = reinterpret_cast<const float4*>(w + (size_t)code * DIM)[lane];
        reinterpret_cast<float4*>(out_q + (size_t)(rowBase + r) * DIM)[lane] = v;
    }
}

extern "C" void kernel_launch(void* const* d_in, const int* in_sizes, int n_in,
                              void* d_out, int out_size, void* d_ws, size_t ws_size,
                              hipStream_t stream) {
    const float* x = (const float*)d_in[0];   // (16384, 256) fp32
    const float* w = (const float*)d_in[1];   // (8192, 256) fp32
    float* out_q = (float*)d_out;                           // 16384*256 quantized
    float* out_idx = (float*)d_out + (size_t)NROWS * DIM;   // 16384 indices (as fp32)
    float* wsq = (float*)d_ws;                              // 8192 floats
    float* xsq = (float*)d_ws + NCODES;                     // 16384 floats

    xsq_kernel<<<NROWS / 256, 256, 0, stream>>>(x, xsq);
    wsq_kernel<<<NCODES / 4, 256, 0, stream>>>(w, wsq);
    vq_argmin_kernel<<<NROWS / BM, NTHREADS, 0, stream>>>(x, w, wsq, xsq, out_q, out_idx);
}

// Round 3
// 299.775 us; speedup vs baseline: 3.0935x; 3.0935x over previous
//
#include <hip/hip_runtime.h>
#include <hip/hip_bf16.h>

#define NROWS 16384
#define NCODES 8192
#define DIM 256
#define BM 64
#define BN 512
#define NTILES (NCODES / BN)              // 16
#define NCHUNKS (NTILES * 4)              // 64 chunks of k=64
#define CAP 24
#define MARGIN 3.0e-4f

typedef __attribute__((ext_vector_type(8))) short bf16x8;
typedef __attribute__((ext_vector_type(4))) float f32x4;

__device__ inline unsigned short f2bf(float f) {
    union { __hip_bfloat16 h; unsigned short u; } cv;
    cv.h = __float2bfloat16(f);
    return cv.u;
}
__device__ inline unsigned f2ord(float f) {
    unsigned u = __float_as_uint(f);
    return u ^ ((u >> 31) ? 0xFFFFFFFFu : 0x80000000u);
}
__device__ inline float ord2f(unsigned u) {
    unsigned v = (u & 0x80000000u) ? (u ^ 0x80000000u) : ~u;
    return __uint_as_float(v);
}

// EXACT numpy pairwise sum-of-squares for a 256-vector:
// split 128+128; each 128 uses 8 stride-8 accumulators combined
// ((r0+r1)+(r2+r3))+((r4+r5)+(r6+r7)). Validated bit-exact in round 2.
__device__ float pairwise256_sq(const float4* p) {
    float res[2];
    #pragma unroll
    for (int h = 0; h < 2; ++h) {
        float r[8];
        #pragma unroll
        for (int j = 0; j < 8; ++j) r[j] = 0.0f;
        #pragma unroll
        for (int g = 0; g < 16; ++g) {
            float4 v0 = p[h * 32 + g * 2];
            float4 v1 = p[h * 32 + g * 2 + 1];
            r[0] = __fadd_rn(r[0], __fmul_rn(v0.x, v0.x));
            r[1] = __fadd_rn(r[1], __fmul_rn(v0.y, v0.y));
            r[2] = __fadd_rn(r[2], __fmul_rn(v0.z, v0.z));
            r[3] = __fadd_rn(r[3], __fmul_rn(v0.w, v0.w));
            r[4] = __fadd_rn(r[4], __fmul_rn(v1.x, v1.x));
            r[5] = __fadd_rn(r[5], __fmul_rn(v1.y, v1.y));
            r[6] = __fadd_rn(r[6], __fmul_rn(v1.z, v1.z));
            r[7] = __fadd_rn(r[7], __fmul_rn(v1.w, v1.w));
        }
        res[h] = __fadd_rn(__fadd_rn(__fadd_rn(r[0], r[1]), __fadd_rn(r[2], r[3])),
                           __fadd_rn(__fadd_rn(r[4], r[5]), __fadd_rn(r[6], r[7])));
    }
    return __fadd_rn(res[0], res[1]);
}

__global__ __launch_bounds__(256) void xsq_kernel(const float* __restrict__ x,
                                                  float* __restrict__ xsq) {
    int row = blockIdx.x * 256 + threadIdx.x;
    xsq[row] = pairwise256_sq(reinterpret_cast<const float4*>(x + (size_t)row * DIM));
}

__global__ __launch_bounds__(256) void wsq_kernel(const float* __restrict__ w,
                                                  float* __restrict__ wsq) {
    int code = blockIdx.x * 256 + threadIdx.x;
    wsq[code] = pairwise256_sq(reinterpret_cast<const float4*>(w + (size_t)code * DIM));
}

// Pre-swizzle W into MFMA B-fragment order (bf16):
// flat unit tid = (k32*512 + c16)*64 + L holds 8 bf16 =
//   W[c16*16 + (L&15)][k32*32 + (L>>4)*8 + j]
__global__ __launch_bounds__(256) void wfrag_kernel(const float* __restrict__ w,
                                                    unsigned short* __restrict__ whf) {
    int tid = blockIdx.x * 256 + threadIdx.x;      // 0 .. 262143
    int L = tid & 63;
    int rest = tid >> 6;
    int c16 = rest & 511;
    int k32 = rest >> 9;
    int code = c16 * 16 + (L & 15);
    int k = k32 * 32 + (L >> 4) * 8;
    const float4* p = reinterpret_cast<const float4*>(w + (size_t)code * DIM + k);
    float4 u0 = p[0], u1 = p[1];
    unsigned short tmp[8];
    tmp[0] = f2bf(u0.x); tmp[1] = f2bf(u0.y); tmp[2] = f2bf(u0.z); tmp[3] = f2bf(u0.w);
    tmp[4] = f2bf(u1.x); tmp[5] = f2bf(u1.y); tmp[6] = f2bf(u1.z); tmp[7] = f2bf(u1.w);
    *reinterpret_cast<uint4*>(whf + (size_t)tid * 8) = *reinterpret_cast<uint4*>(tmp);
}

__global__ __launch_bounds__(512, 2)
void vq_main(const float* __restrict__ x, const float* __restrict__ w,
             const unsigned short* __restrict__ whf,
             const float* __restrict__ wsq, const float* __restrict__ xsq,
             float* __restrict__ out_q, float* __restrict__ out_idx) {
    __shared__ unsigned short bbuf[2][BN * 64];   // 2 x 64 KB, fragment-linear
    __shared__ unsigned rowmin[BM];
    __shared__ int cnt[BM];
    __shared__ int cand[BM][CAP];
    __shared__ unsigned long long best64[BM];
    __shared__ int rowBest[BM];

    const int tid = threadIdx.x;
    const int lane = tid & 63;
    const int wv = tid >> 6;          // wave id = code-group
    const int lm = lane & 15;
    const int lq = lane >> 4;
    const int rowBase = blockIdx.x * BM;

    if (tid < BM) { rowmin[tid] = 0xFFFFFFFFu; cnt[tid] = 0; best64[tid] = ~0ull; }

    // ---- A fragments in registers: lane holds x[rowBase+rg*16+lm][k32*32+lq*8+j] ----
    bf16x8 afr[4][8];
    #pragma unroll
    for (int rg = 0; rg < 4; ++rg) {
        const float* xr = x + (size_t)(rowBase + rg * 16 + lm) * DIM + lq * 8;
        #pragma unroll
        for (int k32 = 0; k32 < 8; ++k32) {
            float4 u0 = *reinterpret_cast<const float4*>(xr + k32 * 32);
            float4 u1 = *reinterpret_cast<const float4*>(xr + k32 * 32 + 4);
            bf16x8 a;
            a[0] = (short)f2bf(u0.x); a[1] = (short)f2bf(u0.y);
            a[2] = (short)f2bf(u0.z); a[3] = (short)f2bf(u0.w);
            a[4] = (short)f2bf(u1.x); a[5] = (short)f2bf(u1.y);
            a[6] = (short)f2bf(u1.z); a[7] = (short)f2bf(u1.w);
            afr[rg][k32] = a;
        }
    }

    // async stage of chunk g (k=64 slice of a 512-code tile) into bbuf[g&1]
    auto stage = [&](int g) {
        int t = g >> 2;
        unsigned short* lbuf = &bbuf[g & 1][0];
        #pragma unroll
        for (int i = 0; i < 8; ++i) {
            int f = wv * 8 + i;                       // fragment 0..63
            int k32 = (g & 3) * 2 + (f >> 5);
            int c16 = t * 32 + (f & 31);
            const unsigned short* gp = whf + (((size_t)(k32 * 512 + c16)) * 64 + lane) * 8;
            unsigned short* lp = lbuf + f * 512;      // wave-uniform base; HW adds lane*16B
            __builtin_amdgcn_global_load_lds(
                (const __attribute__((address_space(1))) unsigned int*)gp,
                (__attribute__((address_space(3))) unsigned int*)lp, 16, 0, 0);
        }
    };

    stage(0);

    for (int t = 0; t < NTILES; ++t) {
        f32x4 acc[4][4];
        #pragma unroll
        for (int rg = 0; rg < 4; ++rg)
            #pragma unroll
            for (int cf = 0; cf < 4; ++cf)
                acc[rg][cf] = (f32x4){0.f, 0.f, 0.f, 0.f};

        #pragma unroll
        for (int ch = 0; ch < 4; ++ch) {
            int g = t * 4 + ch;
            __syncthreads();                 // chunk g staged; buf (g+1)&1 free
            if (g + 1 < NCHUNKS) stage(g + 1);
            const unsigned short* buf = &bbuf[g & 1][0];
            #pragma unroll
            for (int kl = 0; kl < 2; ++kl) {
                int k32 = ch * 2 + kl;       // static -> afr indexed statically
                #pragma unroll
                for (int cf = 0; cf < 4; ++cf) {
                    bf16x8 b = *reinterpret_cast<const bf16x8*>(
                        buf + (kl * 32 + wv * 4 + cf) * 512 + lane * 8);
                    #pragma unroll
                    for (int rg = 0; rg < 4; ++rg)
                        acc[rg][cf] = __builtin_amdgcn_mfma_f32_16x16x32_bf16(
                            afr[rg][k32], b, acc[rg][cf], 0, 0, 0);
                }
            }
        }

        // ---- approx score phase: s = wsq - 2*dot (xsq const per row) ----
        float wq[4];
        #pragma unroll
        for (int cf = 0; cf < 4; ++cf) wq[cf] = wsq[t * BN + wv * 64 + cf * 16 + lm];

        #pragma unroll
        for (int rg = 0; rg < 4; ++rg) {
            #pragma unroll
            for (int r = 0; r < 4; ++r) {
                float m = fminf(fminf(wq[0] - 2.f * acc[rg][0][r],
                                      wq[1] - 2.f * acc[rg][1][r]),
                                fminf(wq[2] - 2.f * acc[rg][2][r],
                                      wq[3] - 2.f * acc[rg][3][r]));
                m = fminf(m, __shfl_xor(m, 1, 64));
                m = fminf(m, __shfl_xor(m, 2, 64));
                m = fminf(m, __shfl_xor(m, 4, 64));
                m = fminf(m, __shfl_xor(m, 8, 64));
                if (lm == rg * 4 + r)
                    atomicMin(&rowmin[rg * 16 + lq * 4 + r], f2ord(m));
            }
        }
        __syncthreads();
        // collect candidates within margin of running min (superset of true winner)
        #pragma unroll
        for (int rg = 0; rg < 4; ++rg) {
            #pragma unroll
            for (int r = 0; r < 4; ++r) {
                int row = rg * 16 + lq * 4 + r;
                float limit = ord2f(rowmin[row]) + MARGIN;
                #pragma unroll
                for (int cf = 0; cf < 4; ++cf) {
                    float s = wq[cf] - 2.f * acc[rg][cf][r];
                    if (s <= limit) {
                        int pos = atomicAdd(&cnt[row], 1);
                        if (pos < CAP) cand[row][pos] = t * BN + wv * 64 + cf * 16 + lm;
                    }
                }
            }
        }
    }
    __syncthreads();

    // ---- exact rescore (bit-identical to round-2 validated formula) ----
    for (int slot = tid; slot < BM * CAP; slot += 512) {
        int row = slot / CAP, pos = slot % CAP;
        int n = cnt[row] < CAP ? cnt[row] : CAP;
        if (pos < n) {
            int c = cand[row][pos];
            const float* xr = x + (size_t)(rowBase + row) * DIM;
            const float* wr = w + (size_t)c * DIM;
            float d = 0.f;
            for (int k = 0; k < DIM; k += 4) {
                float4 a = *reinterpret_cast<const float4*>(xr + k);
                float4 b = *reinterpret_cast<const float4*>(wr + k);
                d = fmaf(a.x, b.x, d);
                d = fmaf(a.y, b.y, d);
                d = fmaf(a.z, b.z, d);
                d = fmaf(a.w, b.w, d);
            }
            float t1 = __fadd_rn(xsq[rowBase + row], wsq[c]);
            float s = __fsub_rn(t1, __fadd_rn(d, d));
            unsigned long long key =
                ((unsigned long long)__float_as_uint(s) << 32) | (unsigned)c;
            atomicMin(&best64[row], key);   // s>0 -> bit order = float order; lex (s, idx)
        }
    }
    __syncthreads();
    if (tid < BM) {
        int idx = (int)(best64[tid] & 0xFFFFFFFFu);
        rowBest[tid] = idx;
        out_idx[rowBase + tid] = (float)idx;
    }
    __syncthreads();

    // gather winning codewords, coalesced float4
    #pragma unroll
    for (int it = 0; it < 8; ++it) {
        int r = it * 8 + wv;
        int code = rowBest[r];
        float4 v = reinterpret_cast<const float4*>(w + (size_t)code * DIM)[lane];
        reinterpret_cast<float4*>(out_q + (size_t)(rowBase + r) * DIM)[lane] = v;
    }
}

extern "C" void kernel_launch(void* const* d_in, const int* in_sizes, int n_in,
                              void* d_out, int out_size, void* d_ws, size_t ws_size,
                              hipStream_t stream) {
    const float* x = (const float*)d_in[0];   // (16384, 256) fp32
    const float* w = (const float*)d_in[1];   // (8192, 256) fp32
    float* out_q = (float*)d_out;
    float* out_idx = (float*)d_out + (size_t)NROWS * DIM;

    unsigned short* whf = (unsigned short*)d_ws;                    // 4 MB bf16 frags
    float* wsq = (float*)((char*)d_ws + (size_t)NCODES * DIM * 2);  // 32 KB
    float* xsq = wsq + NCODES;                                      // 64 KB

    wfrag_kernel<<<(NCODES * DIM / 8) / 256, 256, 0, stream>>>(w, whf);
    wsq_kernel<<<NCODES / 256, 256, 0, stream>>>(w, wsq);
    xsq_kernel<<<NROWS / 256, 256, 0, stream>>>(x, xsq);
    vq_main<<<NROWS / BM, 512, 0, stream>>>(x, w, whf, wsq, xsq, out_q, out_idx);
}